// Round 1
// baseline (458.819 us; speedup 1.0000x reference)
//
#include <hip/hip_runtime.h>

// RoiAlign (TF crop_and_resize, bilinear, extrapolation_value=0)
// boxes: [B, N, 4] f32 pixel coords (x1, y1, x2, y2)
// fpn:   [B, H, W, C] f32 (NHWC, C innermost)
// out:   [B, N, 14, 14, C] f32
//
// R1/R2: nt output stores keep fpn L3-resident (822 MB issued reads vs
//        268 MB distinct; cacheable stores were evicting it).
// R3:   streaming prefetch. rocprof showed the roi dispatch itself runs
//       <162 us (absent from top-5; the 433 us dur includes harness poison
//       fills). Remaining kernel gap vs the 75 us perfect-L3 floor is
//       attributed to the COLD 268 MB fetch being issued as random 2 KB
//       chunks (box order). Per image, 256 prefetch blocks dispatched
//       AHEAD of that image's gather blocks stream the 67 MB image
//       linearly into L2/L3, converting scattered HBM reads into a
//       sequential stream; gather corner loads then hit L3.
constexpr int CROP_H = 14;
constexpr int CROP_W = 14;
constexpr int B = 4, N = 256, H = 256, W = 256, C = 256;
constexpr int C4 = C / 4;                                   // float4 per pixel
constexpr int POS_PER_IMG = N * CROP_H * CROP_W;            // 50176
constexpr int GATHER_BLOCKS_PER_IMG = POS_PER_IMG / 4;      // 12544
constexpr int PREFETCH_BLOCKS_PER_IMG = 256;
constexpr int BLOCKS_PER_IMG = GATHER_BLOCKS_PER_IMG + PREFETCH_BLOCKS_PER_IMG; // 12800
constexpr size_t IMG_FLOAT4 = (size_t)H * W * C4;           // 4,194,304 float4 = 67 MB

typedef float vfloat4 __attribute__((ext_vector_type(4)));

__global__ __launch_bounds__(256) void roi_align_kernel(
    const float* __restrict__ boxes,
    const float* __restrict__ fpn,
    float* __restrict__ out) {
  const int b = blockIdx.x / BLOCKS_PER_IMG;
  const int r = blockIdx.x % BLOCKS_PER_IMG;

  if (r < PREFETCH_BLOCKS_PER_IMG) {
    // ---- Linear L3-warming stream of image b (read-only, result sunk). ----
    // Dispatched before this image's gather blocks; raised priority so the
    // stream stays ahead of the gather waves sharing the CU.
    __builtin_amdgcn_s_setprio(3);
    const float4* __restrict__ src =
        (const float4*)fpn + (size_t)b * IMG_FLOAT4;
    constexpr int CHUNK = (int)(IMG_FLOAT4 / PREFETCH_BLOCKS_PER_IMG); // 16384 float4 = 256 KB
    const size_t base = (size_t)r * CHUNK + threadIdx.x;
    float acc = 0.0f;
#pragma unroll 4
    for (int k = 0; k < CHUNK / 256; ++k) {                 // 64 coalesced 4 KB wave-loads
      float4 v = src[base + (size_t)k * 256];
      acc += v.x + v.y + v.z + v.w;  // consume all lanes of the dwordx4
    }
    asm volatile("" :: "v"(acc));    // keep loads alive (no DCE)
    __builtin_amdgcn_s_setprio(0);
    return;
  }

  // ---- Gather path: identical numerics to R2 (absmax-preserving). ----
  // One 64-lane wave per output position (b,n,i,j); lane covers 4 channels.
  const int wave = threadIdx.x >> 6;
  const int lane = threadIdx.x & 63;
  const int p = (r - PREFETCH_BLOCKS_PER_IMG) * 4 + wave;   // [0, POS_PER_IMG)

  int j = p % CROP_W;
  int t = p / CROP_W;
  int i = t % CROP_H;
  int n = t / CROP_H;                                       // [0, N)
  const int pos = b * POS_PER_IMG + p;                      // global output position

  const float* bx = boxes + (size_t)(b * N + n) * 4;
  float x1 = bx[0], y1 = bx[1], x2 = bx[2], y2 = bx[3];

  // Replicate the reference's exact fp32 normalization sequence.
  const float Hf = (float)H, Wf = (float)W;
  float ny1 = y1 / Hf * Hf / (Hf - 1.0f);
  float nx1 = x1 / Wf * Wf / (Wf - 1.0f);
  float ny2 = (y2 / Hf * Hf - 1.0f) / (Hf - 1.0f);
  float nx2 = (x2 / Wf * Wf - 1.0f) / (Wf - 1.0f);

  float ty = (float)i / (float)(CROP_H - 1);
  float tx = (float)j / (float)(CROP_W - 1);
  float ys = (ny1 + (ny2 - ny1) * ty) * (Hf - 1.0f);
  float xs = (nx1 + (nx2 - nx1) * tx) * (Wf - 1.0f);

  bool valid = (ys >= 0.0f) && (ys <= Hf - 1.0f) &&
               (xs >= 0.0f) && (xs <= Wf - 1.0f);

  float y0f = floorf(ys), x0f = floorf(xs);
  float wy = ys - y0f, wx = xs - x0f;
  int y0  = (int)fminf(fmaxf(y0f,        0.0f), Hf - 1.0f);
  int y1i = (int)fminf(fmaxf(y0f + 1.0f, 0.0f), Hf - 1.0f);
  int x0  = (int)fminf(fmaxf(x0f,        0.0f), Wf - 1.0f);
  int x1i = (int)fminf(fmaxf(x0f + 1.0f, 0.0f), Wf - 1.0f);

  const float4* f4 = (const float4*)fpn;
  int rb = b * H;
  size_t i00 = (size_t)((rb + y0)  * W + x0)  * C4 + lane;
  size_t i01 = (size_t)((rb + y0)  * W + x1i) * C4 + lane;
  size_t i10 = (size_t)((rb + y1i) * W + x0)  * C4 + lane;
  size_t i11 = (size_t)((rb + y1i) * W + x1i) * C4 + lane;

  float4 tl = f4[i00];
  float4 tr = f4[i01];
  float4 bl = f4[i10];
  float4 br = f4[i11];

  float w00 = (1.0f - wy) * (1.0f - wx);
  float w01 = (1.0f - wy) * wx;
  float w10 = wy * (1.0f - wx);
  float w11 = wy * wx;

  vfloat4 o;
  o.x = tl.x * w00 + tr.x * w01 + bl.x * w10 + br.x * w11;
  o.y = tl.y * w00 + tr.y * w01 + bl.y * w10 + br.y * w11;
  o.z = tl.z * w00 + tr.z * w01 + bl.z * w10 + br.z * w11;
  o.w = tl.w * w00 + tr.w * w01 + bl.w * w10 + br.w * w11;
  if (!valid) { o.x = 0.0f; o.y = 0.0f; o.z = 0.0f; o.w = 0.0f; }

  // Non-temporal store: don't let the 205 MB output stream evict fpn from L3.
  vfloat4* dst = (vfloat4*)out + (size_t)pos * C4 + lane;
  __builtin_nontemporal_store(o, dst);
}

extern "C" void kernel_launch(void* const* d_in, const int* in_sizes, int n_in,
                              void* d_out, int out_size, void* d_ws, size_t ws_size,
                              hipStream_t stream) {
  const float* boxes = (const float*)d_in[0];  // [B, N, 4]
  const float* fpn   = (const float*)d_in[1];  // [B, H, W, C]
  float* out = (float*)d_out;                  // [B, N, 14, 14, C]

  dim3 grid(B * BLOCKS_PER_IMG), block(256);   // 51200 blocks: 256 prefetch + 12544 gather per image
  hipLaunchKernelGGL(roi_align_kernel, grid, block, 0, stream, boxes, fpn, out);
}